// Round 9
// baseline (173.657 us; speedup 1.0000x reference)
//
#include <hip/hip_runtime.h>
#include <hip/hip_bf16.h>

#define MDIM 49
#define INF 128
#define OUTF 128
#define BDIM 16384
#define BT 64
#define M_PER_BLOCK 7
#define M_CHUNKS (MDIM / M_PER_BLOCK)        // 7
#define BLOCKS_B (BDIM / BT)                 // 256

typedef __attribute__((ext_vector_type(8))) short bf16x8;
typedef __attribute__((ext_vector_type(4))) float f32x4;

static __device__ __forceinline__ short f2bf(float f) {
  __hip_bfloat16 h = __float2bfloat16(f);
  union { __hip_bfloat16 h; unsigned short u; } c;
  c.h = h;
  return (short)c.u;
}

static __device__ __forceinline__ bf16x8 cvt8(f32x4 a, f32x4 b) {
  bf16x8 r;
  r[0] = f2bf(a[0]); r[1] = f2bf(a[1]); r[2] = f2bf(a[2]); r[3] = f2bf(a[3]);
  r[4] = f2bf(b[0]); r[5] = f2bf(b[1]); r[6] = f2bf(b[2]); r[7] = f2bf(b[3]);
  return r;
}

// LDS barrier that does NOT drain vmcnt: ds-op ordering only (lgkmcnt).
// Private global prefetch loads legally stay in flight across it.
static __device__ __forceinline__ void lds_barrier() {
  asm volatile("s_waitcnt lgkmcnt(0)\n\ts_barrier" ::: "memory");
}

__global__ __launch_bounds__(256) void so3_linear_kernel(
    const float* __restrict__ in, const float* __restrict__ wt,
    const float* __restrict__ bias, float* __restrict__ out) {
  const int mlo  = blockIdx.x * M_PER_BLOCK;  // m in [mlo, mlo+7)
  const int blk  = blockIdx.y;                // b-chunk 0..255
  const int tid  = threadIdx.x;
  const int lane = tid & 63;
  const int wv   = tid >> 6;                  // wave 0..3

  // single-buffered bf16 staging tile; +8 shorts pad (272 B stride)
  __shared__ short lds[BT][INF + 8];

  const int colbase = wv * 32;
  const int col0    = colbase + (lane & 15);
  const int krow    = (lane >> 4) * 8;

  float biasv[2];
  biasv[0] = bias[col0];
  biasv[1] = bias[col0 + 16];

  // staging map: thread -> (row r0 + 16p, 8-float chunk c8)
  const int c8 = (tid & 15) * 8;
  const int r0 = tid >> 4;
  const int b0 = blk * BT;

  const size_t rowstride = (size_t)MDIM * INF;  // 6272 floats between consecutive b

  // per-row base for this thread's staging chunk (column offset added per m)
  const float* ipbase = in + (size_t)(b0 + r0) * rowstride + c8;

  // weight fragments (operand B), reloaded only when l changes
  bf16x8 bfrag[2][4];
  int lprev = -1;

  // prefetch input tile for first m
  f32x4 pf[8];
  {
    const float* ip = ipbase + (size_t)mlo * INF;
#pragma unroll
    for (int p = 0; p < 4; ++p) {
      pf[2 * p]     = *(const f32x4*)(ip + p * 16 * rowstride);
      pf[2 * p + 1] = *(const f32x4*)(ip + p * 16 * rowstride + 4);
    }
  }

  for (int mi = 0; mi < M_PER_BLOCK; ++mi) {
    const int m = mlo + mi;

    // l = floor(sqrt(m)); reload weight fragments only on change (L2-resident)
    int l = 0;
    while ((l + 1) * (l + 1) <= m) ++l;
    if (l != lprev) {
      lprev = l;
      const float* wl = wt + (size_t)l * OUTF * INF;
#pragma unroll
      for (int ct = 0; ct < 2; ++ct) {
        const float* wp = wl + (size_t)(col0 + ct * 16) * INF + krow;
#pragma unroll
        for (int ks = 0; ks < 4; ++ks) {
          f32x4 w0 = *(const f32x4*)(wp + ks * 32);
          f32x4 w1 = *(const f32x4*)(wp + ks * 32 + 4);
          bfrag[ct][ks] = cvt8(w0, w1);
        }
      }
    }

    // convert current tile regs -> bf16 LDS
#pragma unroll
    for (int p = 0; p < 4; ++p) {
      *(bf16x8*)&lds[r0 + 16 * p][c8] = cvt8(pf[2 * p], pf[2 * p + 1]);
    }

    // prefetch next m's tile: ADJACENT 512 B chunks of the same rows
    // (page-local), in flight across the lgkm-only barriers below.
    if (mi + 1 < M_PER_BLOCK) {
      const float* ip = ipbase + (size_t)(m + 1) * INF;
#pragma unroll
      for (int p = 0; p < 4; ++p) {
        pf[2 * p]     = *(const f32x4*)(ip + p * 16 * rowstride);
        pf[2 * p + 1] = *(const f32x4*)(ip + p * 16 * rowstride + 4);
      }
    }

    lds_barrier();  // staging visible; prefetch NOT drained

    // compute: wave covers all 64 rows x its 32 o-cols, K=128
    f32x4 acc[4][2];
#pragma unroll
    for (int rt = 0; rt < 4; ++rt)
#pragma unroll
      for (int ct = 0; ct < 2; ++ct)
        acc[rt][ct] = (f32x4){0.f, 0.f, 0.f, 0.f};

#pragma unroll
    for (int rt = 0; rt < 4; ++rt) {
      const int arow = rt * 16 + (lane & 15);
#pragma unroll
      for (int ks = 0; ks < 4; ++ks) {
        bf16x8 a = *(const bf16x8*)&lds[arow][ks * 32 + krow];
        acc[rt][0] = __builtin_amdgcn_mfma_f32_16x16x32_bf16(
            a, bfrag[0][ks], acc[rt][0], 0, 0, 0);
        acc[rt][1] = __builtin_amdgcn_mfma_f32_16x16x32_bf16(
            a, bfrag[1][ks], acc[rt][1], 0, 0, 0);
      }
    }

    // epilogue (measured-best): C/D col=lane&15 (=o), row=(lane>>4)*4+j (=b)
#pragma unroll
    for (int rt = 0; rt < 4; ++rt) {
      const int rbase = b0 + rt * 16 + (lane >> 4) * 4;
#pragma unroll
      for (int ct = 0; ct < 2; ++ct) {
        const int col = colbase + ct * 16 + (lane & 15);
        const float badd = (m == 0) ? biasv[ct] : 0.0f;
#pragma unroll
        for (int j = 0; j < 4; ++j) {
          out[((size_t)(rbase + j) * MDIM + m) * OUTF + col] = acc[rt][ct][j] + badd;
        }
      }
    }

    lds_barrier();  // ds_reads done before next tile's ds_writes
  }
}

extern "C" void kernel_launch(void* const* d_in, const int* in_sizes, int n_in,
                              void* d_out, int out_size, void* d_ws, size_t ws_size,
                              hipStream_t stream) {
  const float* in   = (const float*)d_in[0];
  const float* wt   = (const float*)d_in[1];
  const float* bias = (const float*)d_in[2];
  float* out        = (float*)d_out;
  dim3 grid(M_CHUNKS, BLOCKS_B);
  so3_linear_kernel<<<grid, dim3(256), 0, stream>>>(in, wt, bias, out);
}